// Round 15
// baseline (1994.021 us; speedup 1.0000x reference)
//
#include <hip/hip_runtime.h>
#include <hip/hip_bf16.h>

#define B_ 4
#define N_ 16384
#define S_ 1024
#define K_ 32

typedef float f32x2 __attribute__((ext_vector_type(2)));

// wave64 max of nonnegative floats via DPP (identity 0 from bound_ctrl fill).
__device__ __forceinline__ float wave_max_nonneg(float x) {
#define DPPSTEP(ctrl, rm)                                                              \
  {                                                                                    \
    int s_ = __builtin_amdgcn_update_dpp(__float_as_int(x), __float_as_int(x), (ctrl), \
                                         (rm), 0xf, true);                             \
    x = fmaxf(x, __int_as_float(s_));                                                  \
  }
  DPPSTEP(0x111, 0xf)  // row_shr:1
  DPPSTEP(0x112, 0xf)  // row_shr:2
  DPPSTEP(0x114, 0xf)  // row_shr:4
  DPPSTEP(0x118, 0xf)  // row_shr:8
  DPPSTEP(0x142, 0xa)  // row_bcast:15 -> rows 1,3
  DPPSTEP(0x143, 0xc)  // row_bcast:31 -> rows 2,3
#undef DPPSTEP
  return __int_as_float(__builtin_amdgcn_readlane(__float_as_int(x), 63));
}

// wave64 max of u32 (identity 0).
__device__ __forceinline__ unsigned wave_umax(unsigned x) {
#define DPPSTEP(ctrl, rm)                                                             \
  {                                                                                   \
    unsigned s_ = (unsigned)__builtin_amdgcn_update_dpp((int)x, (int)x, (ctrl), (rm), \
                                                        0xf, true);                   \
    x = (x > s_) ? x : s_;                                                            \
  }
  DPPSTEP(0x111, 0xf)
  DPPSTEP(0x112, 0xf)
  DPPSTEP(0x114, 0xf)
  DPPSTEP(0x118, 0xf)
  DPPSTEP(0x142, 0xa)
  DPPSTEP(0x143, 0xc)
#undef DPPSTEP
  return (unsigned)__builtin_amdgcn_readlane((int)x, 63);
}

// ---------------- transpose features [B,64,N] -> [B,N,64] ----------------
__global__ __launch_bounds__(256) void k_transpose(const float* __restrict__ f,
                                                   float* __restrict__ ft) {
  __shared__ float tile[64][65];
  int b = blockIdx.x >> 8;
  int n0 = (blockIdx.x & 255) << 6;
  int t = threadIdx.x;
  int r = t >> 6, c = t & 63;
#pragma unroll
  for (int i = 0; i < 16; ++i) {
    int ch = r + i * 4;
    tile[ch][c] = f[((size_t)b * 64 + ch) * N_ + n0 + c];
  }
  __syncthreads();
#pragma unroll
  for (int i = 0; i < 16; ++i) {
    int n = r + i * 4;
    ft[((size_t)b * N_ + n0 + n) * 64 + c] = tile[c][n];
  }
}

// ---------------- furthest point sampling with EXACT pruning ----------------
// R13/R14 pruning skeleton, with ZERO in-loop global memory accesses:
// the single submitter lane's candidate always lies in its OWN 16-point
// chunk (pos in [base, base+16)), so its coords are selected from the
// lane's own px/py/pz registers (8-way cndmask, ~50 instrs) instead of a
// 300-900 cyc S4 global load on the barrier critical path (the R14
// regression). Replay path: 1 atomic + 1 LDS write by the cached submitter.
// Post-barrier decode: slot64 LDS read -> cxyz LDS read. Semantics identical
// to R13 (exact md, same candidate key, same winner).
__global__ __attribute__((amdgpu_flat_work_group_size(1024, 1024)))
__attribute__((amdgpu_waves_per_eu(4, 4))) void k_fps(const float* __restrict__ xyz,
                                                      float* __restrict__ out,
                                                      float4* __restrict__ S4all) {
#pragma clang fp contract(off)
  const int b = blockIdx.x, t = threadIdx.x;
  const int w = t >> 6;
  const float* X = xyz + (size_t)b * N_ * 3;
  float4* S4 = S4all + (size_t)b * N_;

  __shared__ unsigned hist[64], cfill[64];
  __shared__ unsigned long long slot64[2];
  __shared__ float4 cxyz[2][16];

  if (t < 64) hist[t] = 0u;
  if (t == 0) { slot64[0] = 0ull; slot64[1] = 0ull; }
  __syncthreads();

  // phase A: cell histogram
  unsigned mycell[16];
#pragma unroll
  for (int q = 0; q < 16; ++q) {
    int p = (q << 10) + t;
    float x = X[p * 3], y = X[p * 3 + 1], z = X[p * 3 + 2];
    int cx = (int)(x * 4.f); cx = cx > 3 ? 3 : cx;
    int cy = (int)(y * 4.f); cy = cy > 3 ? 3 : cy;
    int cz = (int)(z * 4.f); cz = cz > 3 ? 3 : cz;
    mycell[q] = ((unsigned)cx << 4) | ((unsigned)cy << 2) | (unsigned)cz;
    atomicAdd(&hist[mycell[q]], 1u);
  }
  __syncthreads();
  // phase B: exclusive prefix -> cfill
  if (t == 0) {
    unsigned s = 0;
    for (int i = 0; i < 64; ++i) { unsigned h = hist[i]; cfill[i] = s; s += h; }
  }
  __syncthreads();
  // phase C: scatter sorted {x,y,z,orig} to global scratch
#pragma unroll
  for (int q = 0; q < 16; ++q) {
    int p = (q << 10) + t;
    float x = X[p * 3], y = X[p * 3 + 1], z = X[p * 3 + 2];
    unsigned pos = atomicAdd(&cfill[mycell[q]], 1u);
    S4[pos] = make_float4(x, y, z, __uint_as_float((unsigned)p));
  }
  __threadfence();
  __syncthreads();

  // phase D: gather my contiguous 16 sorted points into registers + bbox
  f32x2 px0, px1, px2, px3, px4, px5, px6, px7;
  f32x2 py0, py1, py2, py3, py4, py5, py6, py7;
  f32x2 pz0, pz1, pz2, pz3, pz4, pz5, pz6, pz7;
  f32x2 md0, md1, md2, md3, md4, md5, md6, md7;
  unsigned oi0, oi1, oi2, oi3, oi4, oi5, oi6, oi7;
  const int base = t << 4;
#define LOADP(j)                                                     \
  {                                                                  \
    float4 a = S4[base + 2 * j], c = S4[base + 2 * j + 1];           \
    px##j = (f32x2){a.x, c.x};                                       \
    py##j = (f32x2){a.y, c.y};                                       \
    pz##j = (f32x2){a.z, c.z};                                       \
    oi##j = (__float_as_uint(a.w) << 16) | (__float_as_uint(c.w) & 0xFFFFu); \
    md##j = (f32x2){1e10f, 1e10f};                                   \
  }
  LOADP(0) LOADP(1) LOADP(2) LOADP(3) LOADP(4) LOADP(5) LOADP(6) LOADP(7)
#undef LOADP
#define EMIN __builtin_elementwise_min
#define EMAX __builtin_elementwise_max
  f32x2 tmn = EMIN(EMIN(EMIN(px0, px1), EMIN(px2, px3)), EMIN(EMIN(px4, px5), EMIN(px6, px7)));
  f32x2 tmx = EMAX(EMAX(EMAX(px0, px1), EMAX(px2, px3)), EMAX(EMAX(px4, px5), EMAX(px6, px7)));
  float bxmin = fminf(tmn.x, tmn.y), bxmax = fmaxf(tmx.x, tmx.y);
  tmn = EMIN(EMIN(EMIN(py0, py1), EMIN(py2, py3)), EMIN(EMIN(py4, py5), EMIN(py6, py7)));
  tmx = EMAX(EMAX(EMAX(py0, py1), EMAX(py2, py3)), EMAX(EMAX(py4, py5), EMAX(py6, py7)));
  float bymin = fminf(tmn.x, tmn.y), bymax = fmaxf(tmx.x, tmx.y);
  tmn = EMIN(EMIN(EMIN(pz0, pz1), EMIN(pz2, pz3)), EMIN(EMIN(pz4, pz5), EMIN(pz6, pz7)));
  tmx = EMAX(EMAX(EMAX(pz0, pz1), EMAX(pz2, pz3)), EMAX(EMAX(pz4, pz5), EMAX(pz6, pz7)));
  float bzmin = fminf(tmn.x, tmn.y), bzmax = fmaxf(tmx.x, tmx.y);

  float lmax = 1e10f;               // cached max of my 16 md (exact)
  unsigned long long wcand = 0ull;  // cached candidate (submitter lane only)
  float4 wcoord = make_float4(0.f, 0.f, 0.f, 0.f);  // cached candidate coords

  float c0x = X[0], c0y = X[1], c0z = X[2];
  f32x2 ncx = (f32x2){-c0x, -c0x};
  f32x2 ncy = (f32x2){-c0y, -c0y};
  f32x2 ncz = (f32x2){-c0z, -c0z};

  int sld = 0;
  for (int it = 0;; ++it) {
    if (t == 0) {
      float* o = out + ((size_t)b * S_ + it) * 3;
      o[0] = -ncx.x; o[1] = -ncy.x; o[2] = -ncz.x;
    }
    if (it == S_ - 1) break;

    // chunk prune test: provably-safe skip (slack 1e-3 >> fp error ~1e-6)
    float ccx = -ncx.x, ccy = -ncy.x, ccz = -ncz.x;
    float dxm = fmaxf(fmaxf(bxmin - ccx, ccx - bxmax), 0.f);
    float dym = fmaxf(fmaxf(bymin - ccy, ccy - bymax), 0.f);
    float dzm = fmaxf(fmaxf(bzmin - ccz, ccz - bzmax), 0.f);
    float dmin2 = (dxm * dxm + dym * dym) + dzm * dzm;
    bool needs = !(dmin2 * 0.999f > lmax);
    unsigned long long mball = __ballot(needs);

    if (mball) {  // wave-uniform: >=1 chunk in this wave must update
      if (needs) {
#define FPS_UPD(j)                            \
  {                                           \
    f32x2 dx = px##j + ncx;                   \
    f32x2 dy = py##j + ncy;                   \
    f32x2 dz = pz##j + ncz;                   \
    f32x2 ss = (dx * dx + dy * dy) + dz * dz; \
    md##j = EMIN(md##j, ss);                  \
  }
        FPS_UPD(0) FPS_UPD(1) FPS_UPD(2) FPS_UPD(3)
        FPS_UPD(4) FPS_UPD(5) FPS_UPD(6) FPS_UPD(7)
#undef FPS_UPD
        f32x2 m01 = EMAX(md0, md1), m23 = EMAX(md2, md3);
        f32x2 m45 = EMAX(md4, md5), m67 = EMAX(md6, md7);
        f32x2 mm = EMAX(EMAX(m01, m23), EMAX(m45, m67));
        lmax = fmaxf(mm.x, mm.y);
      }
      float wm = wave_max_nonneg(lmax);  // full-exec DPP reduce
      unsigned bestX = 0xFFFFFFFFu;
      if (lmax == wm) {
        // min ORIGINAL index among my slots attaining wm
#define SCANS(j)                                                              \
  {                                                                           \
    unsigned oA = oi##j >> 16;                                                \
    unsigned XA = (oA << 14) | (unsigned)(base + 2 * j);                      \
    if (md##j.x == wm && XA < bestX) bestX = XA;                              \
    unsigned oB = oi##j & 0xFFFFu;                                            \
    unsigned XB = (oB << 14) | (unsigned)(base + 2 * j + 1);                  \
    if (md##j.y == wm && XB < bestX) bestX = XB;                              \
  }
        SCANS(0) SCANS(1) SCANS(2) SCANS(3) SCANS(4) SCANS(5) SCANS(6) SCANS(7)
#undef SCANS
      }
      unsigned rr = wave_umax(~bestX);  // wave winner = min X
      wcand = 0ull;
      if (((~bestX) == rr) && (bestX != 0xFFFFFFFFu)) {  // unique submitter lane
        unsigned long long cand =
            ((unsigned long long)__float_as_uint(wm) << 28) |
            (unsigned long long)((~bestX) & 0xFFFFFFFu);
        // candidate is in MY chunk: coords from my own registers (no memory)
        int j2 = (int)(bestX & 16383u) - base;  // 0..15
        int qq = j2 >> 1, hi = j2 & 1;
        f32x2 vx = px0, vy = py0, vz = pz0;
        if (qq == 1) { vx = px1; vy = py1; vz = pz1; }
        if (qq == 2) { vx = px2; vy = py2; vz = pz2; }
        if (qq == 3) { vx = px3; vy = py3; vz = pz3; }
        if (qq == 4) { vx = px4; vy = py4; vz = pz4; }
        if (qq == 5) { vx = px5; vy = py5; vz = pz5; }
        if (qq == 6) { vx = px6; vy = py6; vz = pz6; }
        if (qq == 7) { vx = px7; vy = py7; vz = pz7; }
        float xc = hi ? vx.y : vx.x;
        float yc = hi ? vy.y : vy.x;
        float zc = hi ? vz.y : vz.x;
        float4 cw4 = make_float4(xc, yc, zc, 0.f);
        wcoord = cw4;
        wcand = cand;
        cxyz[sld][w] = cw4;
        atomicMax(&slot64[sld], cand);
      }
    } else {
      if (wcand) {  // replay cached candidate (exact: nothing in wave changed)
        cxyz[sld][w] = wcoord;
        atomicMax(&slot64[sld], wcand);
      }
    }
    if (t == 0) slot64[sld ^ 1] = 0ull;  // reset next slot before the barrier
    __syncthreads();

    unsigned long long pkv = slot64[sld];
    unsigned low = (unsigned)(pkv & 0xFFFFFFFull);
    unsigned Xv = 0xFFFFFFFu ^ low;  // (orig<<14)|pos of winner
    unsigned pos = Xv & 16383u;
    float4 cw = cxyz[sld][(pos >> 10) & 15u];  // winner wave's published coords
    ncx = (f32x2){-cw.x, -cw.x};
    ncy = (f32x2){-cw.y, -cw.y};
    ncz = (f32x2){-cw.z, -cw.z};
    sld ^= 1;
  }
#undef EMIN
#undef EMAX
}

// ---------------- ball query: 1 wave per center ----------------
__global__ __launch_bounds__(256) void k_ball(const float* __restrict__ xyz,
                                              const float* __restrict__ nx,
                                              int* __restrict__ bidx) {
#pragma clang fp contract(off)
  int gw = (blockIdx.x * 256 + threadIdx.x) >> 6;
  int l = threadIdx.x & 63;
  int b = gw >> 10;
  const float* X = xyz + (size_t)b * N_ * 3;
  float cx = nx[(size_t)gw * 3 + 0], cy = nx[(size_t)gw * 3 + 1], cz = nx[(size_t)gw * 3 + 2];
  float xn2 = (cx * cx + cy * cy) + cz * cz;
  int* out = bidx + gw * K_;
  int have = 0, first = -1;
  for (int n0 = 0; n0 < N_; n0 += 64) {
    int p = n0 + l;
    float x = X[p * 3 + 0], y = X[p * 3 + 1], z = X[p * 3 + 2];
    float pn2 = (x * x + y * y) + z * z;
    float dt = (x * cx + y * cy) + z * cz;
    float d2 = (xn2 + pn2) - 2.0f * dt;  // exact replica of ref's expanded form
    unsigned long long m = __ballot(d2 < 0.039999999105930328f);  // float(0.04), NOT 0.2f*0.2f
    if (first < 0 && m) first = n0 + (__ffsll(m) - 1);
    if (m & (1ull << l)) {
      int pos = have + __popcll(m & ((1ull << l) - 1ull));
      if (pos < K_) out[pos] = p;
    }
    have += __popcll(m);
    if (have >= K_) break;
  }
  if (have < K_ && l >= have && l < K_) out[l] = first;  // pad with first neighbor
}

// ---------------- gather + conv1 (67 -> 64), 8 centers per block ----------------
__global__ __launch_bounds__(256) void k_conv1(const float* __restrict__ xyz,
                                               const float* __restrict__ ft,
                                               const float* __restrict__ nx,
                                               const int* __restrict__ bidx,
                                               const float* __restrict__ W0,
                                               float* __restrict__ y1) {
  __shared__ float w0t[67][64];
  __shared__ float Xs[32][69];  // stride 69: (69k+i)%32 = (5k+i)%32 conflict-free
  __shared__ int lidx[32];
  __shared__ float lctr[3];
  const int t = threadIdx.x;
  for (int idx = t; idx < 67 * 64; idx += 256) {
    int i = idx >> 6, c = idx & 63;
    w0t[i][c] = W0[c * 67 + i];
  }
  const int k = t & 31, cb = (t >> 5) << 3;
  const int gk = t >> 3, c8 = (t & 7) << 3;
  for (int cc = 0; cc < 8; ++cc) {
    int cs = blockIdx.x * 8 + cc;
    int b = cs >> 10;
    __syncthreads();
    if (t < 32) lidx[t] = bidx[cs * K_ + t];
    if (t < 3) lctr[t] = nx[(size_t)cs * 3 + t];
    __syncthreads();
    {
      int p = lidx[gk];
      const float* src = ft + ((size_t)b * N_ + p) * 64 + c8;
      float4 v0 = *(const float4*)src;
      float4 v1 = *(const float4*)(src + 4);
      float* xr = &Xs[gk][3 + c8];
      xr[0] = v0.x; xr[1] = v0.y; xr[2] = v0.z; xr[3] = v0.w;
      xr[4] = v1.x; xr[5] = v1.y; xr[6] = v1.z; xr[7] = v1.w;
    }
    if (t < 32) {
      int p = lidx[t];
      const float* pp = xyz + ((size_t)b * N_ + p) * 3;
      Xs[t][0] = pp[0] - lctr[0];
      Xs[t][1] = pp[1] - lctr[1];
      Xs[t][2] = pp[2] - lctr[2];
    }
    __syncthreads();
    float acc[8] = {};
    for (int i = 0; i < 67; ++i) {
      float xv = Xs[k][i];
      const float4 wa = *(const float4*)&w0t[i][cb];
      const float4 wb = *(const float4*)&w0t[i][cb + 4];
      acc[0] = fmaf(wa.x, xv, acc[0]);
      acc[1] = fmaf(wa.y, xv, acc[1]);
      acc[2] = fmaf(wa.z, xv, acc[2]);
      acc[3] = fmaf(wa.w, xv, acc[3]);
      acc[4] = fmaf(wb.x, xv, acc[4]);
      acc[5] = fmaf(wb.y, xv, acc[5]);
      acc[6] = fmaf(wb.z, xv, acc[6]);
      acc[7] = fmaf(wb.w, xv, acc[7]);
    }
    float* dst = y1 + ((size_t)cs * K_ + k) * 64 + cb;
    *(float4*)dst = make_float4(acc[0], acc[1], acc[2], acc[3]);
    *(float4*)(dst + 4) = make_float4(acc[4], acc[5], acc[6], acc[7]);
  }
}

// ---------------- BN1 stats: per-block partials (deterministic) ----------------
__global__ __launch_bounds__(256) void k_stats1(const float* __restrict__ y1,
                                                float* __restrict__ part) {
  int t = threadIdx.x;
  int c = t & 63;
  float s = 0.f, q = 0.f;
  for (int row = blockIdx.x * 4 + (t >> 6); row < B_ * S_ * K_; row += 512 * 4) {
    float v = y1[(size_t)row * 64 + c];
    s += v;
    q = fmaf(v, v, q);
  }
  __shared__ float ls[4][64], lq[4][64];
  ls[t >> 6][c] = s;
  lq[t >> 6][c] = q;
  __syncthreads();
  if (t < 64) {
    float S = (ls[0][t] + ls[1][t]) + (ls[2][t] + ls[3][t]);
    float Q = (lq[0][t] + lq[1][t]) + (lq[2][t] + lq[3][t]);
    part[blockIdx.x * 128 + t] = S;
    part[blockIdx.x * 128 + 64 + t] = Q;
  }
}

// ---------------- reduce [nrow][ncol] partials -> [ncol] ----------------
__global__ void k_red(const float* __restrict__ part, float* __restrict__ outv,
                      int ncol, int nrow) {
  int c = blockIdx.x * 64 + threadIdx.x;
  float a0 = 0, a1 = 0, a2 = 0, a3 = 0;
  for (int r = 0; r < nrow; r += 4) {
    a0 += part[(size_t)(r + 0) * ncol + c];
    a1 += part[(size_t)(r + 1) * ncol + c];
    a2 += part[(size_t)(r + 2) * ncol + c];
    a3 += part[(size_t)(r + 3) * ncol + c];
  }
  outv[c] = (a0 + a1) + (a2 + a3);
}

// ------- BN1-apply + conv2 (64->128) + stats2 partials + max/min over K -------
__global__ __launch_bounds__(256) void k_conv2(const float* __restrict__ y1,
                                               const float* __restrict__ W1,
                                               const float* __restrict__ st1,
                                               const float* __restrict__ g0,
                                               const float* __restrict__ b0,
                                               float* __restrict__ part2,
                                               float* __restrict__ mmax,
                                               float* __restrict__ mmin) {
  __shared__ float w1t[64][128];
  __shared__ float X2[32][69];
  __shared__ float a1s[64], bb1s[64];
  const int t = threadIdx.x;
  if (t < 64) {
    float s = st1[t], q = st1[64 + t];
    float m = s * (1.f / 131072.f);
    float v = fmaxf(q * (1.f / 131072.f) - m * m, 0.f);
    float inv = 1.f / sqrtf(v + 1e-5f);
    float a = g0[t] * inv;
    a1s[t] = a;
    bb1s[t] = b0[t] - m * a;
  }
  for (int idx = t; idx < 64 * 128; idx += 256) {
    int i = idx >> 7, c = idx & 127;
    w1t[i][c] = W1[c * 64 + i];
  }
  const int kg = (t & 7) << 2;   // 4 neighbor slots
  const int cb = (t >> 3) << 2;  // 4 channels
  const int gk = t >> 3, c8 = (t & 7) << 3;
  float ts[4] = {}, tq[4] = {};
  for (int cc = 0; cc < 8; ++cc) {
    int cs = blockIdx.x * 8 + cc;
    int b = cs >> 10, sc = cs & 1023;
    __syncthreads();
    {
      const float* src = y1 + ((size_t)cs * K_ + gk) * 64 + c8;
      float4 v0 = *(const float4*)src;
      float4 v1 = *(const float4*)(src + 4);
      float vv[8] = {v0.x, v0.y, v0.z, v0.w, v1.x, v1.y, v1.z, v1.w};
#pragma unroll
      for (int j = 0; j < 8; ++j) {
        int c = c8 + j;
        X2[gk][c] = fmaxf(fmaf(a1s[c], vv[j], bb1s[c]), 0.f);
      }
    }
    __syncthreads();
    float acc[4][4] = {};
    for (int i = 0; i < 64; ++i) {
      const float4 w = *(const float4*)&w1t[i][cb];
#pragma unroll
      for (int kk = 0; kk < 4; ++kk) {
        float xv = X2[kg + kk][i];
        acc[kk][0] = fmaf(w.x, xv, acc[kk][0]);
        acc[kk][1] = fmaf(w.y, xv, acc[kk][1]);
        acc[kk][2] = fmaf(w.z, xv, acc[kk][2]);
        acc[kk][3] = fmaf(w.w, xv, acc[kk][3]);
      }
    }
    float mx[4], mn[4];
#pragma unroll
    for (int j = 0; j < 4; ++j) {
      mx[j] = fmaxf(fmaxf(acc[0][j], acc[1][j]), fmaxf(acc[2][j], acc[3][j]));
      mn[j] = fminf(fminf(acc[0][j], acc[1][j]), fminf(acc[2][j], acc[3][j]));
      ts[j] += (acc[0][j] + acc[1][j]) + (acc[2][j] + acc[3][j]);
      tq[j] += (acc[0][j] * acc[0][j] + acc[1][j] * acc[1][j]) +
               (acc[2][j] * acc[2][j] + acc[3][j] * acc[3][j]);
    }
#pragma unroll
    for (int off = 1; off < 8; off <<= 1) {
#pragma unroll
      for (int j = 0; j < 4; ++j) {
        mx[j] = fmaxf(mx[j], __shfl_xor(mx[j], off));
        mn[j] = fminf(mn[j], __shfl_xor(mn[j], off));
      }
    }
    if ((t & 7) == 0) {
#pragma unroll
      for (int j = 0; j < 4; ++j) {
        size_t o = ((size_t)b * 128 + cb + j) * 1024 + sc;
        mmax[o] = mx[j];
        mmin[o] = mn[j];
      }
    }
  }
#pragma unroll
  for (int off = 1; off < 8; off <<= 1) {
#pragma unroll
    for (int j = 0; j < 4; ++j) {
      ts[j] += __shfl_xor(ts[j], off);
      tq[j] += __shfl_xor(tq[j], off);
    }
  }
  if ((t & 7) == 0) {
#pragma unroll
    for (int j = 0; j < 4; ++j) {
      part2[blockIdx.x * 256 + cb + j] = ts[j];
      part2[blockIdx.x * 256 + 128 + cb + j] = tq[j];
    }
  }
}

// ---------------- finalize: BN2 affine on max/min + ReLU ----------------
__global__ __launch_bounds__(256) void k_final(const float* __restrict__ st2,
                                               const float* __restrict__ g1,
                                               const float* __restrict__ b1,
                                               const float* __restrict__ mmax,
                                               const float* __restrict__ mmin,
                                               float* __restrict__ out) {
  int tid = blockIdx.x * 256 + threadIdx.x;
  int c = (tid >> 10) & 127;
  float s = st2[c], q = st2[128 + c];
  float m = s * (1.f / 131072.f);
  float v = fmaxf(q * (1.f / 131072.f) - m * m, 0.f);
  float inv = 1.f / sqrtf(v + 1e-5f);
  float a = g1[c] * inv;
  float bb = b1[c] - m * a;
  // max over K of relu(a*x+bb) == relu(a * (a>=0 ? max : min) + bb)
  float x = (a >= 0.f) ? mmax[tid] : mmin[tid];
  out[12288 + tid] = fmaxf(fmaf(a, x, bb), 0.f);
}

extern "C" void kernel_launch(void* const* d_in, const int* in_sizes, int n_in,
                              void* d_out, int out_size, void* d_ws, size_t ws_size,
                              hipStream_t stream) {
  const float* xyz = (const float*)d_in[0];
  const float* features = (const float*)d_in[1];
  const float* W0 = (const float*)d_in[2];
  const float* g0 = (const float*)d_in[3];
  const float* b0 = (const float*)d_in[4];
  const float* W1 = (const float*)d_in[5];
  const float* g1 = (const float*)d_in[6];
  const float* b1 = (const float*)d_in[7];
  float* out = (float*)d_out;
  float* ws = (float*)d_ws;

  float* ft = ws;                                   // 4,194,304 f
  float* y1 = ft + (size_t)4 * 16384 * 64;          // 8,388,608 f (also k_fps sort scratch)
  float* part1 = y1 + (size_t)4 * 1024 * 32 * 64;   // 65,536 f
  float* part2 = part1 + 512 * 128;                 // 131,072 f
  float* st1 = part2 + 512 * 256;                   // 128 f
  float* st2 = st1 + 128;                           // 256 f
  float* mmax = st2 + 256;                          // 524,288 f
  float* mmin = mmax + (size_t)4 * 128 * 1024;      // 524,288 f
  int* bidx = (int*)(mmin + (size_t)4 * 128 * 1024);// 131,072 i
  if (ws_size < (size_t)(13828480 + 131072) * 4) return;  // workspace guard

  float* nxyz = out;  // new_xyz occupies out[0..12288)

  k_transpose<<<1024, 256, 0, stream>>>(features, ft);
  k_fps<<<4, 1024, 0, stream>>>(xyz, nxyz, (float4*)y1);  // y1 free until k_conv1
  k_ball<<<1024, 256, 0, stream>>>(xyz, nxyz, bidx);
  k_conv1<<<512, 256, 0, stream>>>(xyz, ft, nxyz, bidx, W0, y1);
  k_stats1<<<512, 256, 0, stream>>>(y1, part1);
  k_red<<<2, 64, 0, stream>>>(part1, st1, 128, 512);
  k_conv2<<<512, 256, 0, stream>>>(y1, W1, st1, g0, b0, part2, mmax, mmin);
  k_red<<<4, 64, 0, stream>>>(part2, st2, 256, 512);
  k_final<<<2048, 256, 0, stream>>>(st2, g1, b1, mmax, mmin, out);
}

// Round 16
// 1539.683 us; speedup vs baseline: 1.2951x; 1.2951x over previous
//
#include <hip/hip_runtime.h>
#include <hip/hip_bf16.h>

#define B_ 4
#define N_ 16384
#define S_ 1024
#define K_ 32

typedef float f32x2 __attribute__((ext_vector_type(2)));

// wave64 max of nonnegative floats via DPP (identity 0 from bound_ctrl fill).
__device__ __forceinline__ float wave_max_nonneg(float x) {
#define DPPSTEP(ctrl, rm)                                                              \
  {                                                                                    \
    int s_ = __builtin_amdgcn_update_dpp(__float_as_int(x), __float_as_int(x), (ctrl), \
                                         (rm), 0xf, true);                             \
    x = fmaxf(x, __int_as_float(s_));                                                  \
  }
  DPPSTEP(0x111, 0xf)  // row_shr:1
  DPPSTEP(0x112, 0xf)  // row_shr:2
  DPPSTEP(0x114, 0xf)  // row_shr:4
  DPPSTEP(0x118, 0xf)  // row_shr:8
  DPPSTEP(0x142, 0xa)  // row_bcast:15 -> rows 1,3
  DPPSTEP(0x143, 0xc)  // row_bcast:31 -> rows 2,3
#undef DPPSTEP
  return __int_as_float(__builtin_amdgcn_readlane(__float_as_int(x), 63));
}

// ---------------- transpose features [B,64,N] -> [B,N,64] ----------------
__global__ __launch_bounds__(256) void k_transpose(const float* __restrict__ f,
                                                   float* __restrict__ ft) {
  __shared__ float tile[64][65];
  int b = blockIdx.x >> 8;
  int n0 = (blockIdx.x & 255) << 6;
  int t = threadIdx.x;
  int r = t >> 6, c = t & 63;
#pragma unroll
  for (int i = 0; i < 16; ++i) {
    int ch = r + i * 4;
    tile[ch][c] = f[((size_t)b * 64 + ch) * N_ + n0 + c];
  }
  __syncthreads();
#pragma unroll
  for (int i = 0; i < 16; ++i) {
    int n = r + i * 4;
    ft[((size_t)b * N_ + n0 + n) * 64 + c] = tile[c][n];
  }
}

// ---------------- furthest point sampling with EXACT pruning ----------------
// R13 kernel verbatim (measured best: 1320us, passed). QuickFPS-style chunk
// pruning: md only decreases, so for a 16-point chunk with bbox B and cached
// lmax=max(md), dmin(center,B)^2 * 0.999 > lmax proves (float-error margin
// 1e-3 >> 1e-6) that no md in the chunk changes -> skip the update AND
// replay the cached argmax candidate. Counting-sort by 4x4x4 cell (one-time,
// global scratch) makes chunks spatially tight. Candidate packing
// {md_bits:32, ~(orig<<14|pos):28} keeps np.argmax first-max (min ORIGINAL
// index) semantics exactly, independent of the (run-varying) sort order.
__global__ __attribute__((amdgpu_flat_work_group_size(1024, 1024)))
__attribute__((amdgpu_waves_per_eu(4, 4))) void k_fps(const float* __restrict__ xyz,
                                                      float* __restrict__ out,
                                                      float4* __restrict__ S4all) {
#pragma clang fp contract(off)
  const int b = blockIdx.x, t = threadIdx.x;
  const float* X = xyz + (size_t)b * N_ * 3;
  float4* S4 = S4all + (size_t)b * N_;

  __shared__ unsigned hist[64], cfill[64];
  __shared__ unsigned long long slot64[2];

  if (t < 64) hist[t] = 0u;
  if (t == 0) { slot64[0] = 0ull; slot64[1] = 0ull; }
  __syncthreads();

  // phase A: cell histogram
  unsigned mycell[16];
#pragma unroll
  for (int q = 0; q < 16; ++q) {
    int p = (q << 10) + t;
    float x = X[p * 3], y = X[p * 3 + 1], z = X[p * 3 + 2];
    int cx = (int)(x * 4.f); cx = cx > 3 ? 3 : cx;
    int cy = (int)(y * 4.f); cy = cy > 3 ? 3 : cy;
    int cz = (int)(z * 4.f); cz = cz > 3 ? 3 : cz;
    mycell[q] = ((unsigned)cx << 4) | ((unsigned)cy << 2) | (unsigned)cz;
    atomicAdd(&hist[mycell[q]], 1u);
  }
  __syncthreads();
  // phase B: exclusive prefix -> cfill
  if (t == 0) {
    unsigned s = 0;
    for (int i = 0; i < 64; ++i) { unsigned h = hist[i]; cfill[i] = s; s += h; }
  }
  __syncthreads();
  // phase C: scatter sorted {x,y,z,orig} to global scratch
#pragma unroll
  for (int q = 0; q < 16; ++q) {
    int p = (q << 10) + t;
    float x = X[p * 3], y = X[p * 3 + 1], z = X[p * 3 + 2];
    unsigned pos = atomicAdd(&cfill[mycell[q]], 1u);
    S4[pos] = make_float4(x, y, z, __uint_as_float((unsigned)p));
  }
  __threadfence();
  __syncthreads();

  // phase D: gather my contiguous 16 sorted points into registers + bbox
  f32x2 px0, px1, px2, px3, px4, px5, px6, px7;
  f32x2 py0, py1, py2, py3, py4, py5, py6, py7;
  f32x2 pz0, pz1, pz2, pz3, pz4, pz5, pz6, pz7;
  f32x2 md0, md1, md2, md3, md4, md5, md6, md7;
  unsigned oi0, oi1, oi2, oi3, oi4, oi5, oi6, oi7;
  const int base = t << 4;
#define LOADP(j)                                                     \
  {                                                                  \
    float4 a = S4[base + 2 * j], c = S4[base + 2 * j + 1];           \
    px##j = (f32x2){a.x, c.x};                                       \
    py##j = (f32x2){a.y, c.y};                                       \
    pz##j = (f32x2){a.z, c.z};                                       \
    oi##j = (__float_as_uint(a.w) << 16) | (__float_as_uint(c.w) & 0xFFFFu); \
    md##j = (f32x2){1e10f, 1e10f};                                   \
  }
  LOADP(0) LOADP(1) LOADP(2) LOADP(3) LOADP(4) LOADP(5) LOADP(6) LOADP(7)
#undef LOADP
#define EMIN __builtin_elementwise_min
#define EMAX __builtin_elementwise_max
  f32x2 tmn = EMIN(EMIN(EMIN(px0, px1), EMIN(px2, px3)), EMIN(EMIN(px4, px5), EMIN(px6, px7)));
  f32x2 tmx = EMAX(EMAX(EMAX(px0, px1), EMAX(px2, px3)), EMAX(EMAX(px4, px5), EMAX(px6, px7)));
  float bxmin = fminf(tmn.x, tmn.y), bxmax = fmaxf(tmx.x, tmx.y);
  tmn = EMIN(EMIN(EMIN(py0, py1), EMIN(py2, py3)), EMIN(EMIN(py4, py5), EMIN(py6, py7)));
  tmx = EMAX(EMAX(EMAX(py0, py1), EMAX(py2, py3)), EMAX(EMAX(py4, py5), EMAX(py6, py7)));
  float bymin = fminf(tmn.x, tmn.y), bymax = fmaxf(tmx.x, tmx.y);
  tmn = EMIN(EMIN(EMIN(pz0, pz1), EMIN(pz2, pz3)), EMIN(EMIN(pz4, pz5), EMIN(pz6, pz7)));
  tmx = EMAX(EMAX(EMAX(pz0, pz1), EMAX(pz2, pz3)), EMAX(EMAX(pz4, pz5), EMAX(pz6, pz7)));
  float bzmin = fminf(tmn.x, tmn.y), bzmax = fmaxf(tmx.x, tmx.y);

  float lmax = 1e10f;                 // cached max of my 16 md (exact)
  unsigned long long wcand = 0ull;    // cached candidate (candidate lanes only)

  float c0x = X[0], c0y = X[1], c0z = X[2];
  f32x2 ncx = (f32x2){-c0x, -c0x};
  f32x2 ncy = (f32x2){-c0y, -c0y};
  f32x2 ncz = (f32x2){-c0z, -c0z};

  int sld = 0;
  for (int it = 0;; ++it) {
    if (t == 0) {
      float* o = out + ((size_t)b * S_ + it) * 3;
      o[0] = -ncx.x; o[1] = -ncy.x; o[2] = -ncz.x;
    }
    if (it == S_ - 1) break;

    // chunk prune test: provably-safe skip (slack 1e-3 >> fp error ~1e-6)
    float ccx = -ncx.x, ccy = -ncy.x, ccz = -ncz.x;
    float dxm = fmaxf(fmaxf(bxmin - ccx, ccx - bxmax), 0.f);
    float dym = fmaxf(fmaxf(bymin - ccy, ccy - bymax), 0.f);
    float dzm = fmaxf(fmaxf(bzmin - ccz, ccz - bzmax), 0.f);
    float dmin2 = (dxm * dxm + dym * dym) + dzm * dzm;
    bool needs = !(dmin2 * 0.999f > lmax);
    unsigned long long mball = __ballot(needs);

    if (mball) {  // wave-uniform
      if (needs) {
#define FPS_UPD(j)                                  \
  {                                                 \
    f32x2 dx = px##j + ncx;                         \
    f32x2 dy = py##j + ncy;                         \
    f32x2 dz = pz##j + ncz;                         \
    f32x2 ss = (dx * dx + dy * dy) + dz * dz;       \
    md##j = EMIN(md##j, ss);                        \
  }
        FPS_UPD(0) FPS_UPD(1) FPS_UPD(2) FPS_UPD(3)
        FPS_UPD(4) FPS_UPD(5) FPS_UPD(6) FPS_UPD(7)
#undef FPS_UPD
        f32x2 m01 = EMAX(md0, md1), m23 = EMAX(md2, md3);
        f32x2 m45 = EMAX(md4, md5), m67 = EMAX(md6, md7);
        f32x2 mm = EMAX(EMAX(m01, m23), EMAX(m45, m67));
        lmax = fmaxf(mm.x, mm.y);
      }
      float wm = wave_max_nonneg(lmax);  // full-exec DPP reduce
      if (lmax == wm) {
        // min ORIGINAL index among my slots attaining wm
        unsigned bestX = 0xFFFFFFFFu;
#define SCANS(j)                                                              \
  {                                                                           \
    unsigned oA = oi##j >> 16;                                                \
    unsigned XA = (oA << 14) | (unsigned)(base + 2 * j);                      \
    if (md##j.x == wm && XA < bestX) bestX = XA;                              \
    unsigned oB = oi##j & 0xFFFFu;                                            \
    unsigned XB = (oB << 14) | (unsigned)(base + 2 * j + 1);                  \
    if (md##j.y == wm && XB < bestX) bestX = XB;                              \
  }
        SCANS(0) SCANS(1) SCANS(2) SCANS(3) SCANS(4) SCANS(5) SCANS(6) SCANS(7)
#undef SCANS
        unsigned long long cand =
            ((unsigned long long)__float_as_uint(wm) << 28) |
            (unsigned long long)((~bestX) & 0xFFFFFFFu);
        atomicMax(&slot64[sld], cand);
        wcand = cand;
      } else {
        wcand = 0ull;
      }
    } else {
      if (wcand) atomicMax(&slot64[sld], wcand);  // replay cached (exact: nothing changed)
    }
    if (t == 0) slot64[sld ^ 1] = 0ull;  // reset next slot before the barrier
    __syncthreads();

    unsigned long long pkv = slot64[sld];
    unsigned low = (unsigned)(pkv & 0xFFFFFFFull);
    unsigned Xv = 0xFFFFFFFu ^ low;       // (orig<<14)|pos of winner
    unsigned pos = Xv & 16383u;
    float4 cw = S4[pos];                  // uniform broadcast load (L2-hot)
    ncx = (f32x2){-cw.x, -cw.x};
    ncy = (f32x2){-cw.y, -cw.y};
    ncz = (f32x2){-cw.z, -cw.z};
    sld ^= 1;
  }
#undef EMIN
#undef EMAX
}

// ---------------- ball query: 1 wave per center ----------------
__global__ __launch_bounds__(256) void k_ball(const float* __restrict__ xyz,
                                              const float* __restrict__ nx,
                                              int* __restrict__ bidx) {
#pragma clang fp contract(off)
  int gw = (blockIdx.x * 256 + threadIdx.x) >> 6;
  int l = threadIdx.x & 63;
  int b = gw >> 10;
  const float* X = xyz + (size_t)b * N_ * 3;
  float cx = nx[(size_t)gw * 3 + 0], cy = nx[(size_t)gw * 3 + 1], cz = nx[(size_t)gw * 3 + 2];
  float xn2 = (cx * cx + cy * cy) + cz * cz;
  int* out = bidx + gw * K_;
  int have = 0, first = -1;
  for (int n0 = 0; n0 < N_; n0 += 64) {
    int p = n0 + l;
    float x = X[p * 3 + 0], y = X[p * 3 + 1], z = X[p * 3 + 2];
    float pn2 = (x * x + y * y) + z * z;
    float dt = (x * cx + y * cy) + z * cz;
    float d2 = (xn2 + pn2) - 2.0f * dt;  // exact replica of ref's expanded form
    unsigned long long m = __ballot(d2 < 0.039999999105930328f);  // float(0.04), NOT 0.2f*0.2f
    if (first < 0 && m) first = n0 + (__ffsll(m) - 1);
    if (m & (1ull << l)) {
      int pos = have + __popcll(m & ((1ull << l) - 1ull));
      if (pos < K_) out[pos] = p;
    }
    have += __popcll(m);
    if (have >= K_) break;
  }
  if (have < K_ && l >= have && l < K_) out[l] = first;  // pad with first neighbor
}

// ---------------- gather + conv1 (67 -> 64), 8 centers per block ----------------
__global__ __launch_bounds__(256) void k_conv1(const float* __restrict__ xyz,
                                               const float* __restrict__ ft,
                                               const float* __restrict__ nx,
                                               const int* __restrict__ bidx,
                                               const float* __restrict__ W0,
                                               float* __restrict__ y1) {
  __shared__ float w0t[67][64];
  __shared__ float Xs[32][69];  // stride 69: (69k+i)%32 = (5k+i)%32 conflict-free
  __shared__ int lidx[32];
  __shared__ float lctr[3];
  const int t = threadIdx.x;
  for (int idx = t; idx < 67 * 64; idx += 256) {
    int i = idx >> 6, c = idx & 63;
    w0t[i][c] = W0[c * 67 + i];
  }
  const int k = t & 31, cb = (t >> 5) << 3;
  const int gk = t >> 3, c8 = (t & 7) << 3;
  for (int cc = 0; cc < 8; ++cc) {
    int cs = blockIdx.x * 8 + cc;
    int b = cs >> 10;
    __syncthreads();
    if (t < 32) lidx[t] = bidx[cs * K_ + t];
    if (t < 3) lctr[t] = nx[(size_t)cs * 3 + t];
    __syncthreads();
    {
      int p = lidx[gk];
      const float* src = ft + ((size_t)b * N_ + p) * 64 + c8;
      float4 v0 = *(const float4*)src;
      float4 v1 = *(const float4*)(src + 4);
      float* xr = &Xs[gk][3 + c8];
      xr[0] = v0.x; xr[1] = v0.y; xr[2] = v0.z; xr[3] = v0.w;
      xr[4] = v1.x; xr[5] = v1.y; xr[6] = v1.z; xr[7] = v1.w;
    }
    if (t < 32) {
      int p = lidx[t];
      const float* pp = xyz + ((size_t)b * N_ + p) * 3;
      Xs[t][0] = pp[0] - lctr[0];
      Xs[t][1] = pp[1] - lctr[1];
      Xs[t][2] = pp[2] - lctr[2];
    }
    __syncthreads();
    float acc[8] = {};
    for (int i = 0; i < 67; ++i) {
      float xv = Xs[k][i];
      const float4 wa = *(const float4*)&w0t[i][cb];
      const float4 wb = *(const float4*)&w0t[i][cb + 4];
      acc[0] = fmaf(wa.x, xv, acc[0]);
      acc[1] = fmaf(wa.y, xv, acc[1]);
      acc[2] = fmaf(wa.z, xv, acc[2]);
      acc[3] = fmaf(wa.w, xv, acc[3]);
      acc[4] = fmaf(wb.x, xv, acc[4]);
      acc[5] = fmaf(wb.y, xv, acc[5]);
      acc[6] = fmaf(wb.z, xv, acc[6]);
      acc[7] = fmaf(wb.w, xv, acc[7]);
    }
    float* dst = y1 + ((size_t)cs * K_ + k) * 64 + cb;
    *(float4*)dst = make_float4(acc[0], acc[1], acc[2], acc[3]);
    *(float4*)(dst + 4) = make_float4(acc[4], acc[5], acc[6], acc[7]);
  }
}

// ---------------- BN1 stats: per-block partials (deterministic) ----------------
__global__ __launch_bounds__(256) void k_stats1(const float* __restrict__ y1,
                                                float* __restrict__ part) {
  int t = threadIdx.x;
  int c = t & 63;
  float s = 0.f, q = 0.f;
  for (int row = blockIdx.x * 4 + (t >> 6); row < B_ * S_ * K_; row += 512 * 4) {
    float v = y1[(size_t)row * 64 + c];
    s += v;
    q = fmaf(v, v, q);
  }
  __shared__ float ls[4][64], lq[4][64];
  ls[t >> 6][c] = s;
  lq[t >> 6][c] = q;
  __syncthreads();
  if (t < 64) {
    float S = (ls[0][t] + ls[1][t]) + (ls[2][t] + ls[3][t]);
    float Q = (lq[0][t] + lq[1][t]) + (lq[2][t] + lq[3][t]);
    part[blockIdx.x * 128 + t] = S;
    part[blockIdx.x * 128 + 64 + t] = Q;
  }
}

// ---------------- reduce [nrow][ncol] partials -> [ncol] ----------------
__global__ void k_red(const float* __restrict__ part, float* __restrict__ outv,
                      int ncol, int nrow) {
  int c = blockIdx.x * 64 + threadIdx.x;
  float a0 = 0, a1 = 0, a2 = 0, a3 = 0;
  for (int r = 0; r < nrow; r += 4) {
    a0 += part[(size_t)(r + 0) * ncol + c];
    a1 += part[(size_t)(r + 1) * ncol + c];
    a2 += part[(size_t)(r + 2) * ncol + c];
    a3 += part[(size_t)(r + 3) * ncol + c];
  }
  outv[c] = (a0 + a1) + (a2 + a3);
}

// ------- BN1-apply + conv2 (64->128) + stats2 partials + max/min over K -------
__global__ __launch_bounds__(256) void k_conv2(const float* __restrict__ y1,
                                               const float* __restrict__ W1,
                                               const float* __restrict__ st1,
                                               const float* __restrict__ g0,
                                               const float* __restrict__ b0,
                                               float* __restrict__ part2,
                                               float* __restrict__ mmax,
                                               float* __restrict__ mmin) {
  __shared__ float w1t[64][128];
  __shared__ float X2[32][69];
  __shared__ float a1s[64], bb1s[64];
  const int t = threadIdx.x;
  if (t < 64) {
    float s = st1[t], q = st1[64 + t];
    float m = s * (1.f / 131072.f);
    float v = fmaxf(q * (1.f / 131072.f) - m * m, 0.f);
    float inv = 1.f / sqrtf(v + 1e-5f);
    float a = g0[t] * inv;
    a1s[t] = a;
    bb1s[t] = b0[t] - m * a;
  }
  for (int idx = t; idx < 64 * 128; idx += 256) {
    int i = idx >> 7, c = idx & 127;
    w1t[i][c] = W1[c * 64 + i];
  }
  const int kg = (t & 7) << 2;   // 4 neighbor slots
  const int cb = (t >> 3) << 2;  // 4 channels
  const int gk = t >> 3, c8 = (t & 7) << 3;
  float ts[4] = {}, tq[4] = {};
  for (int cc = 0; cc < 8; ++cc) {
    int cs = blockIdx.x * 8 + cc;
    int b = cs >> 10, sc = cs & 1023;
    __syncthreads();
    {
      const float* src = y1 + ((size_t)cs * K_ + gk) * 64 + c8;
      float4 v0 = *(const float4*)src;
      float4 v1 = *(const float4*)(src + 4);
      float vv[8] = {v0.x, v0.y, v0.z, v0.w, v1.x, v1.y, v1.z, v1.w};
#pragma unroll
      for (int j = 0; j < 8; ++j) {
        int c = c8 + j;
        X2[gk][c] = fmaxf(fmaf(a1s[c], vv[j], bb1s[c]), 0.f);
      }
    }
    __syncthreads();
    float acc[4][4] = {};
    for (int i = 0; i < 64; ++i) {
      const float4 w = *(const float4*)&w1t[i][cb];
#pragma unroll
      for (int kk = 0; kk < 4; ++kk) {
        float xv = X2[kg + kk][i];
        acc[kk][0] = fmaf(w.x, xv, acc[kk][0]);
        acc[kk][1] = fmaf(w.y, xv, acc[kk][1]);
        acc[kk][2] = fmaf(w.z, xv, acc[kk][2]);
        acc[kk][3] = fmaf(w.w, xv, acc[kk][3]);
      }
    }
    float mx[4], mn[4];
#pragma unroll
    for (int j = 0; j < 4; ++j) {
      mx[j] = fmaxf(fmaxf(acc[0][j], acc[1][j]), fmaxf(acc[2][j], acc[3][j]));
      mn[j] = fminf(fminf(acc[0][j], acc[1][j]), fminf(acc[2][j], acc[3][j]));
      ts[j] += (acc[0][j] + acc[1][j]) + (acc[2][j] + acc[3][j]);
      tq[j] += (acc[0][j] * acc[0][j] + acc[1][j] * acc[1][j]) +
               (acc[2][j] * acc[2][j] + acc[3][j] * acc[3][j]);
    }
#pragma unroll
    for (int off = 1; off < 8; off <<= 1) {
#pragma unroll
      for (int j = 0; j < 4; ++j) {
        mx[j] = fmaxf(mx[j], __shfl_xor(mx[j], off));
        mn[j] = fminf(mn[j], __shfl_xor(mn[j], off));
      }
    }
    if ((t & 7) == 0) {
#pragma unroll
      for (int j = 0; j < 4; ++j) {
        size_t o = ((size_t)b * 128 + cb + j) * 1024 + sc;
        mmax[o] = mx[j];
        mmin[o] = mn[j];
      }
    }
  }
#pragma unroll
  for (int off = 1; off < 8; off <<= 1) {
#pragma unroll
    for (int j = 0; j < 4; ++j) {
      ts[j] += __shfl_xor(ts[j], off);
      tq[j] += __shfl_xor(tq[j], off);
    }
  }
  if ((t & 7) == 0) {
#pragma unroll
    for (int j = 0; j < 4; ++j) {
      part2[blockIdx.x * 256 + cb + j] = ts[j];
      part2[blockIdx.x * 256 + 128 + cb + j] = tq[j];
    }
  }
}

// ---------------- finalize: BN2 affine on max/min + ReLU ----------------
__global__ __launch_bounds__(256) void k_final(const float* __restrict__ st2,
                                               const float* __restrict__ g1,
                                               const float* __restrict__ b1,
                                               const float* __restrict__ mmax,
                                               const float* __restrict__ mmin,
                                               float* __restrict__ out) {
  int tid = blockIdx.x * 256 + threadIdx.x;
  int c = (tid >> 10) & 127;
  float s = st2[c], q = st2[128 + c];
  float m = s * (1.f / 131072.f);
  float v = fmaxf(q * (1.f / 131072.f) - m * m, 0.f);
  float inv = 1.f / sqrtf(v + 1e-5f);
  float a = g1[c] * inv;
  float bb = b1[c] - m * a;
  // max over K of relu(a*x+bb) == relu(a * (a>=0 ? max : min) + bb)
  float x = (a >= 0.f) ? mmax[tid] : mmin[tid];
  out[12288 + tid] = fmaxf(fmaf(a, x, bb), 0.f);
}

extern "C" void kernel_launch(void* const* d_in, const int* in_sizes, int n_in,
                              void* d_out, int out_size, void* d_ws, size_t ws_size,
                              hipStream_t stream) {
  const float* xyz = (const float*)d_in[0];
  const float* features = (const float*)d_in[1];
  const float* W0 = (const float*)d_in[2];
  const float* g0 = (const float*)d_in[3];
  const float* b0 = (const float*)d_in[4];
  const float* W1 = (const float*)d_in[5];
  const float* g1 = (const float*)d_in[6];
  const float* b1 = (const float*)d_in[7];
  float* out = (float*)d_out;
  float* ws = (float*)d_ws;

  float* ft = ws;                                   // 4,194,304 f
  float* y1 = ft + (size_t)4 * 16384 * 64;          // 8,388,608 f (also k_fps sort scratch)
  float* part1 = y1 + (size_t)4 * 1024 * 32 * 64;   // 65,536 f
  float* part2 = part1 + 512 * 128;                 // 131,072 f
  float* st1 = part2 + 512 * 256;                   // 128 f
  float* st2 = st1 + 128;                           // 256 f
  float* mmax = st2 + 256;                          // 524,288 f
  float* mmin = mmax + (size_t)4 * 128 * 1024;      // 524,288 f
  int* bidx = (int*)(mmin + (size_t)4 * 128 * 1024);// 131,072 i
  if (ws_size < (size_t)(13828480 + 131072) * 4) return;  // workspace guard

  float* nxyz = out;  // new_xyz occupies out[0..12288)

  k_transpose<<<1024, 256, 0, stream>>>(features, ft);
  k_fps<<<4, 1024, 0, stream>>>(xyz, nxyz, (float4*)y1);  // y1 free until k_conv1
  k_ball<<<1024, 256, 0, stream>>>(xyz, nxyz, bidx);
  k_conv1<<<512, 256, 0, stream>>>(xyz, ft, nxyz, bidx, W0, y1);
  k_stats1<<<512, 256, 0, stream>>>(y1, part1);
  k_red<<<2, 64, 0, stream>>>(part1, st1, 128, 512);
  k_conv2<<<512, 256, 0, stream>>>(y1, W1, st1, g0, b0, part2, mmax, mmin);
  k_red<<<4, 64, 0, stream>>>(part2, st2, 256, 512);
  k_final<<<2048, 256, 0, stream>>>(st2, g1, b1, mmax, mmin, out);
}